// Round 1
// baseline (27473.318 us; speedup 1.0000x reference)
//
#include <hip/hip_runtime.h>

#define NB 16384
#define NT 1024

// tanh(x) = 1 - 2/(exp(2x)+1), exp(2x) = exp2(x * 2*log2(e)).
// v_exp_f32 + v_rcp_f32 are ~1 ulp each -> ~2-3e-7 abs error, comparable to fp32 roundoff.
static __device__ __forceinline__ float tanh_fast(float x) {
  float e = __builtin_amdgcn_exp2f(x * 2.88539008177792681f);
  return fmaf(-2.0f, __builtin_amdgcn_rcpf(e + 1.0f), 1.0f);
}

__global__ __launch_bounds__(512)
void node_step_kernel(const float* __restrict__ y0,
                      const float* __restrict__ ts,
                      const float* __restrict__ W1,
                      const float* __restrict__ b1,
                      const float* __restrict__ W2,
                      const float* __restrict__ b2,
                      const float* __restrict__ W3,
                      const float* __restrict__ b3,
                      float* __restrict__ out)
{
  // h1 exchange buffer: [batch-lane][16 quads], XOR-swizzled quad index so both
  // writes and reads run at the LDS 8-access/bank floor (no conflicts).
  __shared__ float4 sH1[64][16];
  __shared__ float  sKp0[8][64];
  __shared__ float  sKp1[8][64];

  const int lane  = (int)(threadIdx.x & 63);          // batch element within block
  const int wv    = __builtin_amdgcn_readfirstlane((int)(threadIdx.x >> 6)); // wave id, uniform
  const int gb    = (int)blockIdx.x * 64 + lane;      // global batch element
  const int jbase = wv * 8;                           // this wave's hidden rows
  const int sw    = lane & 15;                        // LDS quad swizzle

  // Wave-uniform per-row weights (loop-invariant; compiler keeps in SGPR/VGPR).
  float w1a[8], w1b[8], b1r[8], b2r[8], w3a[8], w3b[8];
#pragma unroll
  for (int i = 0; i < 8; ++i) {
    const int j = jbase + i;
    w1a[i] = W1[2*j];
    w1b[i] = W1[2*j+1];
    b1r[i] = b1[j];
    b2r[i] = b2[j];
    w3a[i] = W3[j];        // W3[0][j]
    w3b[i] = W3[64 + j];   // W3[1][j]
  }
  const float b30 = b3[0], b31 = b3[1];

  float yx = y0[2*gb], yy = y0[2*gb+1];

  float2* __restrict__ outv = (float2*)out;
  if (wv == 0) outv[gb] = make_float2(yx, yy);   // SaveAt includes t0

  // Dopri5 tableau, rounded to fp32 from exact rationals (matches np float32 consts).
  const float A21 = (float)(1.0/5.0);
  const float A31 = (float)(3.0/40.0),  A32 = (float)(9.0/40.0);
  const float A41 = (float)(44.0/45.0), A42 = (float)(-56.0/15.0), A43 = (float)(32.0/9.0);
  const float A51 = (float)(19372.0/6561.0), A52 = (float)(-25360.0/2187.0),
              A53 = (float)(64448.0/6561.0), A54 = (float)(-212.0/729.0);
  const float A61 = (float)(9017.0/3168.0), A62 = (float)(-355.0/33.0),
              A63 = (float)(46732.0/5247.0), A64 = (float)(49.0/176.0),
              A65 = (float)(-5103.0/18656.0);
  const float BB1 = (float)(35.0/384.0), BB3 = (float)(500.0/1113.0),
              BB4 = (float)(125.0/192.0), BB5 = (float)(-2187.0/6784.0),
              BB6 = (float)(11.0/84.0);

  float k1x,k1y,k2x,k2y,k3x,k3y,k4x,k4y,k5x,k5y,k6x,k6y;

  for (int t = 0; t < NT-1; ++t) {
    const float dt = ts[t+1] - ts[t];

    // One vector-field eval: (ysx,ysy) -> (kx,ky), all lanes end with k replicated.
    auto EVAL = [&](float ysx, float ysy, float& kx, float& ky) {
      // Phase A: this wave's 8 h1 rows for its 64 batch elements.
      float h[8];
#pragma unroll
      for (int i = 0; i < 8; ++i) {
        float tt = fmaf(w1a[i], ysx, fmaf(w1b[i], ysy, b1r[i]));
        h[i] = tanh_fast(tt);
      }
      sH1[lane][(2*wv)   ^ sw] = make_float4(h[0], h[1], h[2], h[3]);
      sH1[lane][(2*wv+1) ^ sw] = make_float4(h[4], h[5], h[6], h[7]);
      __syncthreads();

      // Phase B: full h1 row for my batch element into 64 VGPRs, then 8 rows of W2.
      float4 H[16];
#pragma unroll
      for (int q = 0; q < 16; ++q) H[q] = sH1[lane][q ^ sw];

      float p0 = 0.0f, p1 = 0.0f;
#pragma unroll
      for (int i = 0; i < 8; ++i) {
        const int j = jbase + i;
        const float4* __restrict__ wrow = (const float4*)(W2 + 64*j); // uniform addr
        float a0 = b2r[i], a1 = 0.0f, a2 = 0.0f, a3 = 0.0f;  // 4-way split: breaks dep chain
#pragma unroll
        for (int q = 0; q < 16; ++q) {
          const float4 wq = wrow[q];
          const float4 hq = H[q];
          a0 = fmaf(wq.x, hq.x, a0);
          a1 = fmaf(wq.y, hq.y, a1);
          a2 = fmaf(wq.z, hq.z, a2);
          a3 = fmaf(wq.w, hq.w, a3);
        }
        const float h2 = tanh_fast((a0 + a1) + (a2 + a3));
        p0 = fmaf(w3a[i], h2, p0);
        p1 = fmaf(w3b[i], h2, p1);
      }
      sKp0[wv][lane] = p0;
      sKp1[wv][lane] = p1;
      __syncthreads();

      // Phase C: every wave reduces the 8 partials (replicated k, no broadcast needed).
      float s0 = b30, s1 = b31;
#pragma unroll
      for (int u = 0; u < 8; ++u) { s0 += sKp0[u][lane]; s1 += sKp1[u][lane]; }
      kx = s0; ky = s1;
    };

    EVAL(yx, yy, k1x, k1y);
    EVAL(fmaf(dt, A21*k1x, yx), fmaf(dt, A21*k1y, yy), k2x, k2y);
    {
      float cx = fmaf(A32, k2x, A31*k1x);
      float cy = fmaf(A32, k2y, A31*k1y);
      EVAL(fmaf(dt, cx, yx), fmaf(dt, cy, yy), k3x, k3y);
    }
    {
      float cx = fmaf(A43, k3x, fmaf(A42, k2x, A41*k1x));
      float cy = fmaf(A43, k3y, fmaf(A42, k2y, A41*k1y));
      EVAL(fmaf(dt, cx, yx), fmaf(dt, cy, yy), k4x, k4y);
    }
    {
      float cx = fmaf(A54, k4x, fmaf(A53, k3x, fmaf(A52, k2x, A51*k1x)));
      float cy = fmaf(A54, k4y, fmaf(A53, k3y, fmaf(A52, k2y, A51*k1y)));
      EVAL(fmaf(dt, cx, yx), fmaf(dt, cy, yy), k5x, k5y);
    }
    {
      float cx = fmaf(A65, k5x, fmaf(A64, k4x, fmaf(A63, k3x, fmaf(A62, k2x, A61*k1x))));
      float cy = fmaf(A65, k5y, fmaf(A64, k4y, fmaf(A63, k3y, fmaf(A62, k2y, A61*k1y))));
      EVAL(fmaf(dt, cx, yx), fmaf(dt, cy, yy), k6x, k6y);
    }
    {
      float cx = fmaf(BB6, k6x, fmaf(BB5, k5x, fmaf(BB4, k4x, fmaf(BB3, k3x, BB1*k1x))));
      float cy = fmaf(BB6, k6y, fmaf(BB5, k5y, fmaf(BB4, k4y, fmaf(BB3, k3y, BB1*k1y))));
      yx = fmaf(dt, cx, yx);
      yy = fmaf(dt, cy, yy);
    }
    if (wv == 0) outv[(t+1)*NB + gb] = make_float2(yx, yy);
  }
}

extern "C" void kernel_launch(void* const* d_in, const int* in_sizes, int n_in,
                              void* d_out, int out_size, void* d_ws, size_t ws_size,
                              hipStream_t stream) {
  const float* y0 = (const float*)d_in[0];
  const float* ts = (const float*)d_in[1];
  const float* W1 = (const float*)d_in[2];
  const float* b1 = (const float*)d_in[3];
  const float* W2 = (const float*)d_in[4];
  const float* b2 = (const float*)d_in[5];
  const float* W3 = (const float*)d_in[6];
  const float* b3 = (const float*)d_in[7];
  float* out = (float*)d_out;

  node_step_kernel<<<dim3(NB/64), dim3(512), 0, stream>>>(
      y0, ts, W1, b1, W2, b2, W3, b3, out);
}

// Round 2
// 27413.239 us; speedup vs baseline: 1.0022x; 1.0022x over previous
//
#include <hip/hip_runtime.h>

#define NB 16384
#define NT 1024

// tanh(x) = 1 - 2/(exp(2x)+1), exp(2x) = exp2(x * 2*log2(e)).
// v_exp_f32 + v_rcp_f32 ~1 ulp each -> ~2-3e-7 abs error.
static __device__ __forceinline__ float tanh_fast(float x) {
  float e = __builtin_amdgcn_exp2f(x * 2.88539008177792681f);
  return fmaf(-2.0f, __builtin_amdgcn_rcpf(e + 1.0f), 1.0f);
}

// block=512 (8 waves, 64 batch elems, 8 hidden rows/wave), grid=256 (1 block/CU).
// __launch_bounds__(512,2): 2 waves/EU min -> 256-VGPR budget. Round-1 ran at
// VGPR_Count=68 which spilled the 64-VGPR H[16] array to scratch (~3x slowdown).
__global__ __launch_bounds__(512, 2)
void node_step_kernel(const float* __restrict__ y0,
                      const float* __restrict__ ts,
                      const float* __restrict__ W1,
                      const float* __restrict__ b1,
                      const float* __restrict__ W2,
                      const float* __restrict__ b2,
                      const float* __restrict__ W3,
                      const float* __restrict__ b3,
                      float* __restrict__ out)
{
  // h1 exchange: [batch-lane][16 quads], XOR-swizzled quad index -> conflict-free
  // b128 writes and reads (verified: SQ_LDS_BANK_CONFLICT = 0 in round 1).
  __shared__ float4 sH1[64][16];
  __shared__ float  sKp0[8][64];   // per-wave partial k, x component
  __shared__ float  sKp1[8][64];   // y component

  const int lane  = (int)(threadIdx.x & 63);          // batch element within block
  const int wv    = __builtin_amdgcn_readfirstlane((int)(threadIdx.x >> 6)); // uniform wave id
  const int gb    = (int)blockIdx.x * 64 + lane;      // global batch element
  const int jbase = wv * 8;                           // this wave's hidden rows
  const int sw    = lane & 15;                        // LDS quad swizzle

  // Loop-invariant LDS row pointers (addresses computed once; inner loop uses
  // compile-time immediate offsets off these).
  float4* const myH  = &sH1[lane][0];
  float*  const myP0 = &sKp0[0][lane];
  float*  const myP1 = &sKp1[0][lane];

  // Wave-uniform per-row weights: j = jbase+i is uniform -> these scalarize to SGPRs.
  float w1a[8], w1b[8], b1r[8], b2r[8], w3a[8], w3b[8];
#pragma unroll
  for (int i = 0; i < 8; ++i) {
    const int j = jbase + i;
    w1a[i] = W1[2*j];
    w1b[i] = W1[2*j+1];
    b1r[i] = b1[j];
    b2r[i] = b2[j];
    w3a[i] = W3[j];        // W3[0][j]
    w3b[i] = W3[64 + j];   // W3[1][j]
  }
  const float b30 = b3[0], b31 = b3[1];
  // Wave-uniform W2 row base (uniform -> s_load path, K$/L1 resident: FETCH 636 KB).
  const float4* const w2base = (const float4*)(W2 + 64*jbase);

  float yx = y0[2*gb], yy = y0[2*gb+1];

  float2* __restrict__ outv = (float2*)out;
  if (wv == 0) outv[gb] = make_float2(yx, yy);   // SaveAt includes t0

  const float A21 = (float)(1.0/5.0);
  const float A31 = (float)(3.0/40.0),  A32 = (float)(9.0/40.0);
  const float A41 = (float)(44.0/45.0), A42 = (float)(-56.0/15.0), A43 = (float)(32.0/9.0);
  const float A51 = (float)(19372.0/6561.0), A52 = (float)(-25360.0/2187.0),
              A53 = (float)(64448.0/6561.0), A54 = (float)(-212.0/729.0);
  const float A61 = (float)(9017.0/3168.0), A62 = (float)(-355.0/33.0),
              A63 = (float)(46732.0/5247.0), A64 = (float)(49.0/176.0),
              A65 = (float)(-5103.0/18656.0);
  const float BB1 = (float)(35.0/384.0), BB3 = (float)(500.0/1113.0),
              BB4 = (float)(125.0/192.0), BB5 = (float)(-2187.0/6784.0),
              BB6 = (float)(11.0/84.0);

  float k1x,k1y,k2x,k2y,k3x,k3y,k4x,k4y,k5x,k5y,k6x,k6y;

  for (int t = 0; t < NT-1; ++t) {
    const float dt = ts[t+1] - ts[t];

    auto EVAL = [&](float ysx, float ysy, float& kx, float& ky) {
      // Phase A: this wave's 8 h1 rows for its 64 batch elements.
      float h[8];
#pragma unroll
      for (int i = 0; i < 8; ++i)
        h[i] = tanh_fast(fmaf(w1a[i], ysx, fmaf(w1b[i], ysy, b1r[i])));
      myH[(2*wv)   ^ sw] = make_float4(h[0], h[1], h[2], h[3]);
      myH[(2*wv+1) ^ sw] = make_float4(h[4], h[5], h[6], h[7]);
      __syncthreads();

      // Phase B: full h1 row for my batch element (64 VGPRs — no spill at 256 budget).
      float4 H[16];
#pragma unroll
      for (int q = 0; q < 16; ++q) H[q] = myH[q ^ sw];

      float p0 = 0.0f, p1 = 0.0f;
#pragma unroll
      for (int i = 0; i < 8; ++i) {
        const float4* __restrict__ wrow = w2base + 16*i;  // uniform addr
        float a0 = b2r[i], a1 = 0.0f, a2 = 0.0f, a3 = 0.0f;
#pragma unroll
        for (int q = 0; q < 16; ++q) {
          const float4 wq = wrow[q];
          const float4 hq = H[q];
          a0 = fmaf(wq.x, hq.x, a0);
          a1 = fmaf(wq.y, hq.y, a1);
          a2 = fmaf(wq.z, hq.z, a2);
          a3 = fmaf(wq.w, hq.w, a3);
        }
        const float h2 = tanh_fast((a0 + a1) + (a2 + a3));
        p0 = fmaf(w3a[i], h2, p0);
        p1 = fmaf(w3b[i], h2, p1);
      }
      myP0[64*wv] = p0;
      myP1[64*wv] = p1;
      __syncthreads();

      // Phase C: every wave reduces the 8 partials (k replicated in all waves).
      float s0 = b30, s1 = b31;
#pragma unroll
      for (int u = 0; u < 8; ++u) { s0 += myP0[64*u]; s1 += myP1[64*u]; }
      kx = s0; ky = s1;
    };

    EVAL(yx, yy, k1x, k1y);
    EVAL(fmaf(dt, A21*k1x, yx), fmaf(dt, A21*k1y, yy), k2x, k2y);
    {
      float cx = fmaf(A32, k2x, A31*k1x);
      float cy = fmaf(A32, k2y, A31*k1y);
      EVAL(fmaf(dt, cx, yx), fmaf(dt, cy, yy), k3x, k3y);
    }
    {
      float cx = fmaf(A43, k3x, fmaf(A42, k2x, A41*k1x));
      float cy = fmaf(A43, k3y, fmaf(A42, k2y, A41*k1y));
      EVAL(fmaf(dt, cx, yx), fmaf(dt, cy, yy), k4x, k4y);
    }
    {
      float cx = fmaf(A54, k4x, fmaf(A53, k3x, fmaf(A52, k2x, A51*k1x)));
      float cy = fmaf(A54, k4y, fmaf(A53, k3y, fmaf(A52, k2y, A51*k1y)));
      EVAL(fmaf(dt, cx, yx), fmaf(dt, cy, yy), k5x, k5y);
    }
    {
      float cx = fmaf(A65, k5x, fmaf(A64, k4x, fmaf(A63, k3x, fmaf(A62, k2x, A61*k1x))));
      float cy = fmaf(A65, k5y, fmaf(A64, k4y, fmaf(A63, k3y, fmaf(A62, k2y, A61*k1y))));
      EVAL(fmaf(dt, cx, yx), fmaf(dt, cy, yy), k6x, k6y);
    }
    {
      float cx = fmaf(BB6, k6x, fmaf(BB5, k5x, fmaf(BB4, k4x, fmaf(BB3, k3x, BB1*k1x))));
      float cy = fmaf(BB6, k6y, fmaf(BB5, k5y, fmaf(BB4, k4y, fmaf(BB3, k3y, BB1*k1y))));
      yx = fmaf(dt, cx, yx);
      yy = fmaf(dt, cy, yy);
    }
    if (wv == 0) outv[(t+1)*NB + gb] = make_float2(yx, yy);
  }
}

extern "C" void kernel_launch(void* const* d_in, const int* in_sizes, int n_in,
                              void* d_out, int out_size, void* d_ws, size_t ws_size,
                              hipStream_t stream) {
  const float* y0 = (const float*)d_in[0];
  const float* ts = (const float*)d_in[1];
  const float* W1 = (const float*)d_in[2];
  const float* b1 = (const float*)d_in[3];
  const float* W2 = (const float*)d_in[4];
  const float* b2 = (const float*)d_in[5];
  const float* W3 = (const float*)d_in[6];
  const float* b3 = (const float*)d_in[7];
  float* out = (float*)d_out;

  node_step_kernel<<<dim3(NB/64), dim3(512), 0, stream>>>(
      y0, ts, W1, b1, W2, b2, W3, b3, out);
}

// Round 3
// 26278.796 us; speedup vs baseline: 1.0455x; 1.0432x over previous
//
#include <hip/hip_runtime.h>

#define NB 16384
#define NT 1024

// tanh(x) = 1 - 2/(exp(2x)+1), exp(2x) = exp2(x * 2*log2(e)).
// v_exp_f32 + v_rcp_f32 ~1 ulp each -> ~2-3e-7 abs error.
static __device__ __forceinline__ float tanh_fast(float x) {
  float e = __builtin_amdgcn_exp2f(x * 2.88539008177792681f);
  return fmaf(-2.0f, __builtin_amdgcn_rcpf(e + 1.0f), 1.0f);
}

// block=512 (8 waves, 64 batch elems/block, 8 hidden rows/wave), grid=256.
// Phase-B loop nest is q-OUTER / row-INNER: only ONE h1 quad live at a time
// (16 ds_read_b128/eval/wave) + 16 persistent accumulators. Rounds 1-2 had
// row-outer with H[16] (64 VGPRs); LLVM refused to keep it resident (VGPR=68)
// and re-issued the LDS/W2 loads per row -> ~8x load traffic, 27.4 ms.
__global__ __launch_bounds__(512, 2)
void node_step_kernel(const float* __restrict__ y0,
                      const float* __restrict__ ts,
                      const float* __restrict__ W1,
                      const float* __restrict__ b1,
                      const float* __restrict__ W2,
                      const float* __restrict__ b2,
                      const float* __restrict__ W3,
                      const float* __restrict__ b3,
                      float* __restrict__ out)
{
  // h1 exchange: [batch-lane][16 quads], XOR-swizzled quad index -> conflict-free
  // b128 writes/reads (verified SQ_LDS_BANK_CONFLICT = 0 in rounds 1-2).
  __shared__ float4 sH1[64][16];
  __shared__ float2 sKp[8][64];   // per-wave partial (kx, ky)

  const int lane  = (int)(threadIdx.x & 63);          // batch element within block
  const int wv    = __builtin_amdgcn_readfirstlane((int)(threadIdx.x >> 6)); // uniform
  const int gb    = (int)blockIdx.x * 64 + lane;      // global batch element
  const int jbase = wv * 8;                           // this wave's hidden rows
  const int sw    = lane & 15;                        // LDS quad swizzle

  float4* const myH  = &sH1[lane][0];
  float2* const myKp = &sKp[0][lane];

  // Wave-uniform per-row weights (uniform index -> SGPRs).
  float w1a[8], w1b[8], b1r[8], b2r[8], w3a[8], w3b[8];
#pragma unroll
  for (int i = 0; i < 8; ++i) {
    const int j = jbase + i;
    w1a[i] = W1[2*j];
    w1b[i] = W1[2*j+1];
    b1r[i] = b1[j];
    b2r[i] = b2[j];
    w3a[i] = W3[j];        // W3[0][j]
    w3b[i] = W3[64 + j];   // W3[1][j]
  }
  const float b30 = b3[0], b31 = b3[1];
  // Wave-uniform W2 base; per-(i,q) offsets are compile-time -> s_load from K$
  // (W2 = 16 KB, exactly K$-resident; FETCH_SIZE 637 KB confirms cache residency).
  const float4* const w2base = (const float4*)(W2 + 64*jbase);

  float yx = y0[2*gb], yy = y0[2*gb+1];

  float2* __restrict__ outv = (float2*)out;
  if (wv == 0) outv[gb] = make_float2(yx, yy);   // SaveAt includes t0

  const float A21 = (float)(1.0/5.0);
  const float A31 = (float)(3.0/40.0),  A32 = (float)(9.0/40.0);
  const float A41 = (float)(44.0/45.0), A42 = (float)(-56.0/15.0), A43 = (float)(32.0/9.0);
  const float A51 = (float)(19372.0/6561.0), A52 = (float)(-25360.0/2187.0),
              A53 = (float)(64448.0/6561.0), A54 = (float)(-212.0/729.0);
  const float A61 = (float)(9017.0/3168.0), A62 = (float)(-355.0/33.0),
              A63 = (float)(46732.0/5247.0), A64 = (float)(49.0/176.0),
              A65 = (float)(-5103.0/18656.0);
  const float BB1 = (float)(35.0/384.0), BB3 = (float)(500.0/1113.0),
              BB4 = (float)(125.0/192.0), BB5 = (float)(-2187.0/6784.0),
              BB6 = (float)(11.0/84.0);

  float k1x,k1y,k2x,k2y,k3x,k3y,k4x,k4y,k5x,k5y,k6x,k6y;

  for (int t = 0; t < NT-1; ++t) {
    const float dt = ts[t+1] - ts[t];

    auto EVAL = [&](float ysx, float ysy, float& kx, float& ky) {
      // Phase A: this wave's 8 h1 rows for its 64 batch elements.
      float h[8];
#pragma unroll
      for (int i = 0; i < 8; ++i)
        h[i] = tanh_fast(fmaf(w1a[i], ysx, fmaf(w1b[i], ysy, b1r[i])));
      myH[(2*wv)   ^ sw] = make_float4(h[0], h[1], h[2], h[3]);
      myH[(2*wv+1) ^ sw] = make_float4(h[4], h[5], h[6], h[7]);
      __syncthreads();

      // Phase B: q-outer. 16 persistent accumulators (2-way split x 8 rows);
      // one ds_read_b128 per q; 8 uniform s_load_dwordx4 per q; 32 FMAs per q.
      float a0[8], a1[8];
#pragma unroll
      for (int i = 0; i < 8; ++i) { a0[i] = b2r[i]; a1[i] = 0.0f; }
#pragma unroll
      for (int q = 0; q < 16; ++q) {
        const float4 hq = myH[q ^ sw];
#pragma unroll
        for (int i = 0; i < 8; ++i) {
          const float4 wq = w2base[16*i + q];   // uniform, const offset
          a0[i] = fmaf(wq.x, hq.x, a0[i]);
          a1[i] = fmaf(wq.y, hq.y, a1[i]);
          a0[i] = fmaf(wq.z, hq.z, a0[i]);
          a1[i] = fmaf(wq.w, hq.w, a1[i]);
        }
      }
      float p0 = 0.0f, p1 = 0.0f;
#pragma unroll
      for (int i = 0; i < 8; ++i) {
        const float h2 = tanh_fast(a0[i] + a1[i]);
        p0 = fmaf(w3a[i], h2, p0);
        p1 = fmaf(w3b[i], h2, p1);
      }
      myKp[64*wv] = make_float2(p0, p1);
      __syncthreads();

      // Phase C: every wave reduces the 8 partials (k replicated in all waves).
      float s0 = b30, s1 = b31;
#pragma unroll
      for (int u = 0; u < 8; ++u) {
        const float2 p = myKp[64*u];
        s0 += p.x; s1 += p.y;
      }
      kx = s0; ky = s1;
    };

    EVAL(yx, yy, k1x, k1y);
    EVAL(fmaf(dt, A21*k1x, yx), fmaf(dt, A21*k1y, yy), k2x, k2y);
    {
      float cx = fmaf(A32, k2x, A31*k1x);
      float cy = fmaf(A32, k2y, A31*k1y);
      EVAL(fmaf(dt, cx, yx), fmaf(dt, cy, yy), k3x, k3y);
    }
    {
      float cx = fmaf(A43, k3x, fmaf(A42, k2x, A41*k1x));
      float cy = fmaf(A43, k3y, fmaf(A42, k2y, A41*k1y));
      EVAL(fmaf(dt, cx, yx), fmaf(dt, cy, yy), k4x, k4y);
    }
    {
      float cx = fmaf(A54, k4x, fmaf(A53, k3x, fmaf(A52, k2x, A51*k1x)));
      float cy = fmaf(A54, k4y, fmaf(A53, k3y, fmaf(A52, k2y, A51*k1y)));
      EVAL(fmaf(dt, cx, yx), fmaf(dt, cy, yy), k5x, k5y);
    }
    {
      float cx = fmaf(A65, k5x, fmaf(A64, k4x, fmaf(A63, k3x, fmaf(A62, k2x, A61*k1x))));
      float cy = fmaf(A65, k5y, fmaf(A64, k4y, fmaf(A63, k3y, fmaf(A62, k2y, A61*k1y))));
      EVAL(fmaf(dt, cx, yx), fmaf(dt, cy, yy), k6x, k6y);
    }
    {
      float cx = fmaf(BB6, k6x, fmaf(BB5, k5x, fmaf(BB4, k4x, fmaf(BB3, k3x, BB1*k1x))));
      float cy = fmaf(BB6, k6y, fmaf(BB5, k5y, fmaf(BB4, k4y, fmaf(BB3, k3y, BB1*k1y))));
      yx = fmaf(dt, cx, yx);
      yy = fmaf(dt, cy, yy);
    }
    if (wv == 0) outv[(t+1)*NB + gb] = make_float2(yx, yy);
  }
}

extern "C" void kernel_launch(void* const* d_in, const int* in_sizes, int n_in,
                              void* d_out, int out_size, void* d_ws, size_t ws_size,
                              hipStream_t stream) {
  const float* y0 = (const float*)d_in[0];
  const float* ts = (const float*)d_in[1];
  const float* W1 = (const float*)d_in[2];
  const float* b1 = (const float*)d_in[3];
  const float* W2 = (const float*)d_in[4];
  const float* b2 = (const float*)d_in[5];
  const float* W3 = (const float*)d_in[6];
  const float* b3 = (const float*)d_in[7];
  float* out = (float*)d_out;

  node_step_kernel<<<dim3(NB/64), dim3(512), 0, stream>>>(
      y0, ts, W1, b1, W2, b2, W3, b3, out);
}

// Round 4
// 23304.739 us; speedup vs baseline: 1.1789x; 1.1276x over previous
//
#include <hip/hip_runtime.h>

#define NB 16384
#define NT 1024

// ---- constant-address-space (AS4) scalar loads: guaranteed s_load from K$ ----
// Wave-uniform weight reads must be SGPR broadcasts, not 64-lane VMEM/LDS reads.
// Casting via uintptr avoids an illegal addrspace-cast diagnostic; AS1/AS4 share
// the flat 64-bit address map on gfx9+.
typedef __attribute__((address_space(4))) const float cfloat;
static __device__ __forceinline__ const cfloat* as_const(const float* p) {
  return (const cfloat*)(unsigned long long)p;
}

// tanh(x) = 1 - 2/(exp(2x)+1); v_exp_f32 + v_rcp_f32, ~2-3e-7 abs error.
static __device__ __forceinline__ float tanh_fast(float x) {
  float e = __builtin_amdgcn_exp2f(x * 2.88539008177792681f);
  return fmaf(-2.0f, __builtin_amdgcn_rcpf(e + 1.0f), 1.0f);
}

// block = 1024 = 16 waves; lane = batch element (64/block); wave = 4 hidden rows.
// grid = 256 (one block/CU). 4 waves/SIMD for stall coverage (rounds 1-3 had 2).
__global__ __launch_bounds__(1024, 4)
void node_step_kernel(const float* __restrict__ y0,
                      const float* __restrict__ ts,
                      const float* __restrict__ W1,
                      const float* __restrict__ b1,
                      const float* __restrict__ W2,
                      const float* __restrict__ b2,
                      const float* __restrict__ W3,
                      const float* __restrict__ b3,
                      float* __restrict__ out)
{
  // h1 exchange: [lane][16 quads], XOR swizzle -> conflict-free b128 (0 conflicts
  // measured rounds 1-3). Quad index now == wave id (16 waves x 4 rows).
  __shared__ float4 sH1[64][16];
  __shared__ float2 sKp[16][64];   // per-wave partial (kx, ky)

  const int lane  = (int)(threadIdx.x & 63);
  const int wv    = __builtin_amdgcn_readfirstlane((int)(threadIdx.x >> 6)); // 0..15
  const int gb    = (int)blockIdx.x * 64 + lane;
  const int jbase = wv * 4;                 // this wave's 4 hidden rows
  const int sw    = lane & 15;              // LDS quad swizzle

  float4* const myH  = &sH1[lane][0];
  float2* const myKp = &sKp[0][lane];

  // Per-row weights -> SGPRs via scalar loads (wave-uniform index).
  const cfloat* W1c = as_const(W1);
  const cfloat* b1c = as_const(b1);
  const cfloat* b2c = as_const(b2);
  const cfloat* W3c = as_const(W3);
  const cfloat* b3c = as_const(b3);
  const cfloat* tsc = as_const(ts);
  const cfloat* w2s = as_const(W2 + 64 * jbase);  // rows jbase..jbase+3

  float w1a[4], w1b[4], b1r[4], b2r[4], w3a[4], w3b[4];
#pragma unroll
  for (int i = 0; i < 4; ++i) {
    const int j = jbase + i;
    w1a[i] = W1c[2*j];
    w1b[i] = W1c[2*j+1];
    b1r[i] = b1c[j];
    b2r[i] = b2c[j];
    w3a[i] = W3c[j];        // W3[0][j]
    w3b[i] = W3c[64 + j];   // W3[1][j]
  }
  const float b30 = b3c[0], b31 = b3c[1];

  float yx = y0[2*gb], yy = y0[2*gb+1];

  float2* __restrict__ outv = (float2*)out;
  if (wv == 0) outv[gb] = make_float2(yx, yy);   // SaveAt includes t0

  const float A21 = (float)(1.0/5.0);
  const float A31 = (float)(3.0/40.0),  A32 = (float)(9.0/40.0);
  const float A41 = (float)(44.0/45.0), A42 = (float)(-56.0/15.0), A43 = (float)(32.0/9.0);
  const float A51 = (float)(19372.0/6561.0), A52 = (float)(-25360.0/2187.0),
              A53 = (float)(64448.0/6561.0), A54 = (float)(-212.0/729.0);
  const float A61 = (float)(9017.0/3168.0), A62 = (float)(-355.0/33.0),
              A63 = (float)(46732.0/5247.0), A64 = (float)(49.0/176.0),
              A65 = (float)(-5103.0/18656.0);
  const float BB1 = (float)(35.0/384.0), BB3 = (float)(500.0/1113.0),
              BB4 = (float)(125.0/192.0), BB5 = (float)(-2187.0/6784.0),
              BB6 = (float)(11.0/84.0);

  float k1x,k1y,k2x,k2y,k3x,k3y,k4x,k4y,k5x,k5y,k6x,k6y;

  for (int t = 0; t < NT-1; ++t) {
    const float dt = tsc[t+1] - tsc[t];

    auto EVAL = [&](float ysx, float ysy, float& kx, float& ky) {
      // Phase A: this wave's 4 h1 rows -> one b128 LDS write.
      float h[4];
#pragma unroll
      for (int i = 0; i < 4; ++i)
        h[i] = tanh_fast(fmaf(w1a[i], ysx, fmaf(w1b[i], ysy, b1r[i])));
      myH[wv ^ sw] = make_float4(h[0], h[1], h[2], h[3]);
      __syncthreads();

      // Phase B: q-groups of 4. Per group: 4 ds_read_b128 (h quads) +
      // 4 rows x 16 scalar W2 floats (backend merges to s_load_dwordx16) +
      // 64 FMAs (v_fmac v_acc, s_w, v_h). 8 independent acc chains.
      float a0[4], a1[4];
#pragma unroll
      for (int i = 0; i < 4; ++i) { a0[i] = b2r[i]; a1[i] = 0.0f; }
#pragma unroll
      for (int qg = 0; qg < 4; ++qg) {
        float4 hq[4];
#pragma unroll
        for (int u = 0; u < 4; ++u) hq[u] = myH[(4*qg + u) ^ sw];
#pragma unroll
        for (int i = 0; i < 4; ++i) {
          const int rb = 64*i + 16*qg;   // row i, cols 16*qg..16*qg+15
#pragma unroll
          for (int u = 0; u < 4; ++u) {
            const float wx = w2s[rb + 4*u + 0];
            const float wy = w2s[rb + 4*u + 1];
            const float wz = w2s[rb + 4*u + 2];
            const float ww = w2s[rb + 4*u + 3];
            a0[i] = fmaf(wx, hq[u].x, a0[i]);
            a1[i] = fmaf(wy, hq[u].y, a1[i]);
            a0[i] = fmaf(wz, hq[u].z, a0[i]);
            a1[i] = fmaf(ww, hq[u].w, a1[i]);
          }
        }
      }
      float p0 = 0.0f, p1 = 0.0f;
#pragma unroll
      for (int i = 0; i < 4; ++i) {
        const float h2 = tanh_fast(a0[i] + a1[i]);
        p0 = fmaf(w3a[i], h2, p0);
        p1 = fmaf(w3b[i], h2, p1);
      }
      myKp[64*wv] = make_float2(p0, p1);
      __syncthreads();

      // Phase C: all waves reduce the 16 partials (k replicated everywhere).
      float s0 = b30, s1 = b31;
#pragma unroll
      for (int u = 0; u < 16; ++u) {
        const float2 p = myKp[64*u];
        s0 += p.x; s1 += p.y;
      }
      kx = s0; ky = s1;
    };

    EVAL(yx, yy, k1x, k1y);
    EVAL(fmaf(dt, A21*k1x, yx), fmaf(dt, A21*k1y, yy), k2x, k2y);
    {
      float cx = fmaf(A32, k2x, A31*k1x);
      float cy = fmaf(A32, k2y, A31*k1y);
      EVAL(fmaf(dt, cx, yx), fmaf(dt, cy, yy), k3x, k3y);
    }
    {
      float cx = fmaf(A43, k3x, fmaf(A42, k2x, A41*k1x));
      float cy = fmaf(A43, k3y, fmaf(A42, k2y, A41*k1y));
      EVAL(fmaf(dt, cx, yx), fmaf(dt, cy, yy), k4x, k4y);
    }
    {
      float cx = fmaf(A54, k4x, fmaf(A53, k3x, fmaf(A52, k2x, A51*k1x)));
      float cy = fmaf(A54, k4y, fmaf(A53, k3y, fmaf(A52, k2y, A51*k1y)));
      EVAL(fmaf(dt, cx, yx), fmaf(dt, cy, yy), k5x, k5y);
    }
    {
      float cx = fmaf(A65, k5x, fmaf(A64, k4x, fmaf(A63, k3x, fmaf(A62, k2x, A61*k1x))));
      float cy = fmaf(A65, k5y, fmaf(A64, k4y, fmaf(A63, k3y, fmaf(A62, k2y, A61*k1y))));
      EVAL(fmaf(dt, cx, yx), fmaf(dt, cy, yy), k6x, k6y);
    }
    {
      float cx = fmaf(BB6, k6x, fmaf(BB5, k5x, fmaf(BB4, k4x, fmaf(BB3, k3x, BB1*k1x))));
      float cy = fmaf(BB6, k6y, fmaf(BB5, k5y, fmaf(BB4, k4y, fmaf(BB3, k3y, BB1*k1y))));
      yx = fmaf(dt, cx, yx);
      yy = fmaf(dt, cy, yy);
    }
    if (wv == 0) outv[(t+1)*NB + gb] = make_float2(yx, yy);
  }
}

extern "C" void kernel_launch(void* const* d_in, const int* in_sizes, int n_in,
                              void* d_out, int out_size, void* d_ws, size_t ws_size,
                              hipStream_t stream) {
  const float* y0 = (const float*)d_in[0];
  const float* ts = (const float*)d_in[1];
  const float* W1 = (const float*)d_in[2];
  const float* b1 = (const float*)d_in[3];
  const float* W2 = (const float*)d_in[4];
  const float* b2 = (const float*)d_in[5];
  const float* W3 = (const float*)d_in[6];
  const float* b3 = (const float*)d_in[7];
  float* out = (float*)d_out;

  node_step_kernel<<<dim3(NB/64), dim3(1024), 0, stream>>>(
      y0, ts, W1, b1, W2, b2, W3, b3, out);
}

// Round 5
// 6124.783 us; speedup vs baseline: 4.4856x; 3.8050x over previous
//
#include <hip/hip_runtime.h>

#define NB 16384
#define NT 1024

typedef _Float16 h8 __attribute__((ext_vector_type(8)));
typedef float    f4 __attribute__((ext_vector_type(4)));

// AS4 scalar loads for wave-uniform weights (s_load from K$ — round-4 win).
typedef __attribute__((address_space(4))) const float cfloat;
static __device__ __forceinline__ const cfloat* as_const(const float* p) {
  return (const cfloat*)(unsigned long long)p;
}

// tanh(x) = 1 - 2/(exp(2x)+1); ~2-3e-7 abs error.
static __device__ __forceinline__ float tanh_fast(float x) {
  float e = __builtin_amdgcn_exp2f(x * 2.88539008177792681f);
  return fmaf(-2.0f, __builtin_amdgcn_rcpf(e + 1.0f), 1.0f);
}

// 2-term f16 split: x = hi + lo, |x - hi - lo| <= ~2^-22 |x|.
static __device__ __forceinline__ void split_f16(float x, _Float16& hi, _Float16& lo) {
  hi = (_Float16)x;
  lo = (_Float16)(x - (float)hi);
}

union H8U { unsigned u[4]; h8 v; };

// Pin a value into a VGPR: prevents the allocator from sinking/rematerializing
// the init-time loads inside the t-loop (the round-1/2 spill-or-reload pathology).
#define PINV(x) asm volatile("" : "+v"(x))

static __device__ __forceinline__ h8 mkh8(const unsigned* u) {
  H8U t; t.u[0] = u[0]; t.u[1] = u[1]; t.u[2] = u[2]; t.u[3] = u[3]; return t.v;
}

// block = 512 (8 waves), 64 batch elems/block, grid = 256 (1 block/CU).
// Layer2 (64x64, 94% of FLOPs) on MFMA f16 2-term split (3 products = fp32-grade);
// layers 1/3 + RK combination on VALU with lane = batch element.
__global__ __launch_bounds__(512, 2)
void node_step_kernel(const float* __restrict__ y0,
                      const float* __restrict__ ts,
                      const float* __restrict__ W1,
                      const float* __restrict__ b1,
                      const float* __restrict__ W2,
                      const float* __restrict__ b2,
                      const float* __restrict__ W3,
                      const float* __restrict__ b3,
                      float* __restrict__ out)
{
  // h1 in MFMA-B layout: row = batch n (0..63), 8 groups of 8 consecutive k,
  // group index XOR-swizzled by (n&7) -> conflict-free b128 writes and reads.
  __shared__ h8 sHhi[64][8];                 // 8 KB
  __shared__ h8 sHlo[64][8];                 // 8 KB
  __shared__ float2 sPart[2][4][16];         // [mhalf][ntile][n&15] layer-3 partials

  const int lane  = (int)(threadIdx.x & 63);
  const int wv    = __builtin_amdgcn_readfirstlane((int)(threadIdx.x >> 6)); // 0..7
  const int gb    = (int)blockIdx.x * 64 + lane;
  const int l15   = lane & 15;
  const int quad  = lane >> 4;
  const int ntile = wv & 3;    // this wave's 16-batch column tile
  const int mhalf = wv >> 2;   // this wave's 32-row half of hidden-out

  // ---- init (once): W2 A-fragments, hi/lo f16, pinned in VGPRs ----
  // A-frag layout (m120-verified): A[m = lane&15][k = quad*8 + j], 8 f16 = 4 VGPRs.
  unsigned afh[2][2][4], afl[2][2][4];       // [mtile-in-half][kstep][dword]
#pragma unroll
  for (int mt = 0; mt < 2; ++mt) {
    const int m = (mhalf*2 + mt)*16 + l15;
#pragma unroll
    for (int ks = 0; ks < 2; ++ks) {
      const float* wp = W2 + m*64 + ks*32 + quad*8;
      H8U hu, lu;
#pragma unroll
      for (int i = 0; i < 8; ++i) {
        _Float16 a, b; split_f16(wp[i], a, b);
        hu.v[i] = a; lu.v[i] = b;
      }
#pragma unroll
      for (int i = 0; i < 4; ++i) {
        afh[mt][ks][i] = hu.u[i];  PINV(afh[mt][ks][i]);
        afl[mt][ks][i] = lu.u[i];  PINV(afl[mt][ks][i]);
      }
    }
  }

  // b2 bias (pre-loaded into acc init) and W3 rows, in C/D layout
  // (m89-verified: col = lane&15, row = quad*4 + reg). Pinned.
  float accb[2][4], w30[2][4], w31[2][4];
#pragma unroll
  for (int mt = 0; mt < 2; ++mt) {
#pragma unroll
    for (int r = 0; r < 4; ++r) {
      const int j2 = (mhalf*2 + mt)*16 + quad*4 + r;
      accb[mt][r] = b2[j2];      PINV(accb[mt][r]);
      w30[mt][r]  = W3[j2];      PINV(w30[mt][r]);
      w31[mt][r]  = W3[64 + j2]; PINV(w31[mt][r]);
    }
  }

  // Layer-1 row weights for this wave's 8 k-rows (wave-uniform -> SGPRs).
  const cfloat* W1c = as_const(W1);
  const cfloat* b1c = as_const(b1);
  const cfloat* b3c = as_const(b3);
  const cfloat* tsc = as_const(ts);
  float w1a[8], w1b[8], b1r[8];
#pragma unroll
  for (int i = 0; i < 8; ++i) {
    const int j = 8*wv + i;
    w1a[i] = W1c[2*j];
    w1b[i] = W1c[2*j+1];
    b1r[i] = b1c[j];
  }
  const float b30 = b3c[0], b31 = b3c[1];

  float yx = y0[2*gb], yy = y0[2*gb+1];

  float2* __restrict__ outv = (float2*)out;
  if (wv == 0) outv[gb] = make_float2(yx, yy);   // SaveAt includes t0

  const float A21 = (float)(1.0/5.0);
  const float A31 = (float)(3.0/40.0),  A32 = (float)(9.0/40.0);
  const float A41 = (float)(44.0/45.0), A42 = (float)(-56.0/15.0), A43 = (float)(32.0/9.0);
  const float A51 = (float)(19372.0/6561.0), A52 = (float)(-25360.0/2187.0),
              A53 = (float)(64448.0/6561.0), A54 = (float)(-212.0/729.0);
  const float A61 = (float)(9017.0/3168.0), A62 = (float)(-355.0/33.0),
              A63 = (float)(46732.0/5247.0), A64 = (float)(49.0/176.0),
              A65 = (float)(-5103.0/18656.0);
  const float BB1 = (float)(35.0/384.0), BB3 = (float)(500.0/1113.0),
              BB4 = (float)(125.0/192.0), BB5 = (float)(-2187.0/6784.0),
              BB6 = (float)(11.0/84.0);

  float k1x,k1y,k2x,k2y,k3x,k3y,k4x,k4y,k5x,k5y,k6x,k6y;

  for (int t = 0; t < NT-1; ++t) {
    const float dt = tsc[t+1] - tsc[t];

    auto EVAL = [&](float ysx, float ysy, float& kx, float& ky) {
      // ---- L1 (lane=batch): 8 k-rows of h1, split to f16 hi/lo, to LDS ----
      h8 hhi, hlo;
#pragma unroll
      for (int i = 0; i < 8; ++i) {
        const float hv = tanh_fast(fmaf(w1a[i], ysx, fmaf(w1b[i], ysy, b1r[i])));
        _Float16 a, b; split_f16(hv, a, b);
        hhi[i] = a; hlo[i] = b;
      }
      const int wslot = wv ^ (lane & 7);
      sHhi[lane][wslot] = hhi;
      sHlo[lane][wslot] = hlo;
      __syncthreads();

      // ---- L2 (MFMA): this wave's 32m x 16n tile of h2 ----
      // B-frag (symmetric to A): B[k = quad*8+j][n = lane&15]; LDS row = global n.
      const int n = (ntile << 4) | l15;
      h8 bh[2], bl[2];
#pragma unroll
      for (int ks = 0; ks < 2; ++ks) {
        const int slot = (ks*4 + quad) ^ (n & 7);
        bh[ks] = sHhi[n][slot];
        bl[ks] = sHlo[n][slot];
      }

      float p0 = 0.0f, p1 = 0.0f;
#pragma unroll
      for (int mt = 0; mt < 2; ++mt) {
        const h8 ah0 = mkh8(afh[mt][0]), al0 = mkh8(afl[mt][0]);
        const h8 ah1 = mkh8(afh[mt][1]), al1 = mkh8(afl[mt][1]);
        f4 c = { accb[mt][0], accb[mt][1], accb[mt][2], accb[mt][3] };
        // smallest terms first; lo*lo dropped (~2^-22 relative)
        c = __builtin_amdgcn_mfma_f32_16x16x32_f16(al0, bh[0], c, 0, 0, 0);
        c = __builtin_amdgcn_mfma_f32_16x16x32_f16(ah0, bl[0], c, 0, 0, 0);
        c = __builtin_amdgcn_mfma_f32_16x16x32_f16(ah0, bh[0], c, 0, 0, 0);
        c = __builtin_amdgcn_mfma_f32_16x16x32_f16(al1, bh[1], c, 0, 0, 0);
        c = __builtin_amdgcn_mfma_f32_16x16x32_f16(ah1, bl[1], c, 0, 0, 0);
        c = __builtin_amdgcn_mfma_f32_16x16x32_f16(ah1, bh[1], c, 0, 0, 0);
#pragma unroll
        for (int r = 0; r < 4; ++r) {
          const float h2 = tanh_fast(c[r]);
          p0 = fmaf(w30[mt][r], h2, p0);
          p1 = fmaf(w31[mt][r], h2, p1);
        }
      }
      // reduce the 4 quads (lanes l, l^16, l^32, l^48 share column n)
      p0 += __shfl_xor(p0, 16); p1 += __shfl_xor(p1, 16);
      p0 += __shfl_xor(p0, 32); p1 += __shfl_xor(p1, 32);
      if (lane < 16) sPart[mhalf][ntile][l15] = make_float2(p0, p1);
      __syncthreads();

      // ---- C (lane=batch): assemble k from the two mhalf partials ----
      const float2 q0 = sPart[0][lane >> 4][l15];
      const float2 q1 = sPart[1][lane >> 4][l15];
      kx = q0.x + q1.x + b30;
      ky = q0.y + q1.y + b31;
    };

    EVAL(yx, yy, k1x, k1y);
    EVAL(fmaf(dt, A21*k1x, yx), fmaf(dt, A21*k1y, yy), k2x, k2y);
    {
      float cx = fmaf(A32, k2x, A31*k1x);
      float cy = fmaf(A32, k2y, A31*k1y);
      EVAL(fmaf(dt, cx, yx), fmaf(dt, cy, yy), k3x, k3y);
    }
    {
      float cx = fmaf(A43, k3x, fmaf(A42, k2x, A41*k1x));
      float cy = fmaf(A43, k3y, fmaf(A42, k2y, A41*k1y));
      EVAL(fmaf(dt, cx, yx), fmaf(dt, cy, yy), k4x, k4y);
    }
    {
      float cx = fmaf(A54, k4x, fmaf(A53, k3x, fmaf(A52, k2x, A51*k1x)));
      float cy = fmaf(A54, k4y, fmaf(A53, k3y, fmaf(A52, k2y, A51*k1y)));
      EVAL(fmaf(dt, cx, yx), fmaf(dt, cy, yy), k5x, k5y);
    }
    {
      float cx = fmaf(A65, k5x, fmaf(A64, k4x, fmaf(A63, k3x, fmaf(A62, k2x, A61*k1x))));
      float cy = fmaf(A65, k5y, fmaf(A64, k4y, fmaf(A63, k3y, fmaf(A62, k2y, A61*k1y))));
      EVAL(fmaf(dt, cx, yx), fmaf(dt, cy, yy), k6x, k6y);
    }
    {
      float cx = fmaf(BB6, k6x, fmaf(BB5, k5x, fmaf(BB4, k4x, fmaf(BB3, k3x, BB1*k1x))));
      float cy = fmaf(BB6, k6y, fmaf(BB5, k5y, fmaf(BB4, k4y, fmaf(BB3, k3y, BB1*k1y))));
      yx = fmaf(dt, cx, yx);
      yy = fmaf(dt, cy, yy);
    }
    if (wv == 0) outv[(t+1)*NB + gb] = make_float2(yx, yy);
  }
}

extern "C" void kernel_launch(void* const* d_in, const int* in_sizes, int n_in,
                              void* d_out, int out_size, void* d_ws, size_t ws_size,
                              hipStream_t stream) {
  const float* y0 = (const float*)d_in[0];
  const float* ts = (const float*)d_in[1];
  const float* W1 = (const float*)d_in[2];
  const float* b1 = (const float*)d_in[3];
  const float* W2 = (const float*)d_in[4];
  const float* b2 = (const float*)d_in[5];
  const float* W3 = (const float*)d_in[6];
  const float* b3 = (const float*)d_in[7];
  float* out = (float*)d_out;

  node_step_kernel<<<dim3(NB/64), dim3(512), 0, stream>>>(
      y0, ts, W1, b1, W2, b2, W3, b3, out);
}

// Round 6
// 5189.400 us; speedup vs baseline: 5.2941x; 1.1802x over previous
//
#include <hip/hip_runtime.h>

#define NB 16384
#define NT 1024

typedef _Float16 h8 __attribute__((ext_vector_type(8)));
typedef float    f4 __attribute__((ext_vector_type(4)));

// AS4 scalar loads for wave-uniform data (ts).
typedef __attribute__((address_space(4))) const float cfloat;
static __device__ __forceinline__ const cfloat* as_const(const float* p) {
  return (const cfloat*)(unsigned long long)p;
}

// tanh(x) = 1 - 2/(exp(2x)+1); ~2-3e-7 abs error; correct saturation at +/-inf.
static __device__ __forceinline__ float tanh_fast(float x) {
  float e = __builtin_amdgcn_exp2f(x * 2.88539008177792681f);
  return fmaf(-2.0f, __builtin_amdgcn_rcpf(e + 1.0f), 1.0f);
}

// 2-term f16 split: x = hi + lo, error ~2^-22 relative (fp32-grade across K=64).
static __device__ __forceinline__ void split_f16(float x, _Float16& hi, _Float16& lo) {
  hi = (_Float16)x;
  lo = (_Float16)(x - (float)hi);
}

union H8U { unsigned u[4]; h8 v; };

// Pin into VGPR: stops the allocator sinking init-time loads into the t-loop
// (round-1/2 pathology). Proven in round 5.
#define PINV(x) asm volatile("" : "+v"(x))

static __device__ __forceinline__ h8 mkh8(const unsigned* u) {
  H8U t; t.u[0] = u[0]; t.u[1] = u[1]; t.u[2] = u[2]; t.u[3] = u[3]; return t.v;
}

// ---- Fully wave-independent design (round 6) ----
// Each wave owns 16 batch columns end-to-end; ZERO __syncthreads, ZERO LDS.
// Round 5 showed the 2 barriers/eval lockstep the co-resident waves and expose
// every latency (~2390 cyc/CU-eval vs ~800 issue floor). Here:
//  - lane (col=lane&15, quad=lane>>4) computes exactly the 16 h1 rows its own
//    MFMA B-fragments need (k = quad*8+j, 32+quad*8+j) -> B materializes in
//    registers, no exchange at all.
//  - full m=64 per wave: 4 m-tiles x 2 k-steps x 3 split-products = 24 MFMA.
//  - k assembled with one 2-step __shfl_xor quad-reduce (only cross-lane ops).
//  - y state replicated across the 4 quads; RK update per-lane.
// block = 256 (4 waves, 64 cols), grid = 256 -> 1024 waves, 1/SIMD, 256 CUs.
__global__ __launch_bounds__(256, 1)
void node_step_kernel(const float* __restrict__ y0,
                      const float* __restrict__ ts,
                      const float* __restrict__ W1,
                      const float* __restrict__ b1,
                      const float* __restrict__ W2,
                      const float* __restrict__ b2,
                      const float* __restrict__ W3,
                      const float* __restrict__ b3,
                      float* __restrict__ out)
{
  const int lane = (int)(threadIdx.x & 63);
  const int wv   = (int)(threadIdx.x >> 6);   // 0..3
  const int col  = lane & 15;                 // batch column within wave (= MFMA n and m lane)
  const int quad = lane >> 4;
  const int gb   = (int)blockIdx.x * 64 + wv * 16 + col;

  // ---- init: W2 A-fragments (full m=64), hi/lo f16, pinned ----
  // A-frag (HW-verified r5): A[m = lane&15][k = quad*8 + j]; k-step adds 32.
  unsigned afh[4][2][4], afl[4][2][4];        // [mtile][kstep][dword]
#pragma unroll
  for (int mt = 0; mt < 4; ++mt) {
    const int m = mt * 16 + col;
#pragma unroll
    for (int ks = 0; ks < 2; ++ks) {
      const float* wp = W2 + m * 64 + ks * 32 + quad * 8;
      H8U hu, lu;
#pragma unroll
      for (int i = 0; i < 8; ++i) {
        _Float16 a, b; split_f16(wp[i], a, b);
        hu.v[i] = a; lu.v[i] = b;
      }
#pragma unroll
      for (int i = 0; i < 4; ++i) {
        afh[mt][ks][i] = hu.u[i];  PINV(afh[mt][ks][i]);
        afl[mt][ks][i] = lu.u[i];  PINV(afl[mt][ks][i]);
      }
    }
  }

  // b2 (acc init) and W3 rows in C/D layout (HW-verified r5: col=lane&15,
  // row = mt*16 + quad*4 + reg). Pinned.
  float accb[4][4], w30[4][4], w31[4][4];
#pragma unroll
  for (int mt = 0; mt < 4; ++mt) {
#pragma unroll
    for (int r = 0; r < 4; ++r) {
      const int j2 = mt * 16 + quad * 4 + r;
      accb[mt][r] = b2[j2];      PINV(accb[mt][r]);
      w30[mt][r]  = W3[j2];      PINV(w30[mt][r]);
      w31[mt][r]  = W3[64 + j2]; PINV(w31[mt][r]);
    }
  }

  // L1 weights for exactly the 16 rows this lane's B-fragments cover:
  // i in 0..7  -> row = quad*8 + i        (k-step 0)
  // i in 8..15 -> row = 32 + quad*8 + i-8 (k-step 1)
  float w1a[16], w1b[16], b1r[16];
#pragma unroll
  for (int i = 0; i < 16; ++i) {
    const int row = (i < 8) ? (quad * 8 + i) : (32 + quad * 8 + (i - 8));
    w1a[i] = W1[2 * row];     PINV(w1a[i]);
    w1b[i] = W1[2 * row + 1]; PINV(w1b[i]);
    b1r[i] = b1[row];         PINV(b1r[i]);
  }
  const cfloat* tsc = as_const(ts);
  const float b30 = b3[0], b31 = b3[1];

  float yx = y0[2 * gb], yy = y0[2 * gb + 1];

  float2* __restrict__ outv = (float2*)out;
  if (quad == 0) outv[gb] = make_float2(yx, yy);   // SaveAt includes t0

  const float A21 = (float)(1.0/5.0);
  const float A31 = (float)(3.0/40.0),  A32 = (float)(9.0/40.0);
  const float A41 = (float)(44.0/45.0), A42 = (float)(-56.0/15.0), A43 = (float)(32.0/9.0);
  const float A51 = (float)(19372.0/6561.0), A52 = (float)(-25360.0/2187.0),
              A53 = (float)(64448.0/6561.0), A54 = (float)(-212.0/729.0);
  const float A61 = (float)(9017.0/3168.0), A62 = (float)(-355.0/33.0),
              A63 = (float)(46732.0/5247.0), A64 = (float)(49.0/176.0),
              A65 = (float)(-5103.0/18656.0);
  const float BB1 = (float)(35.0/384.0), BB3 = (float)(500.0/1113.0),
              BB4 = (float)(125.0/192.0), BB5 = (float)(-2187.0/6784.0),
              BB6 = (float)(11.0/84.0);

  float k1x,k1y,k2x,k2y,k3x,k3y,k4x,k4y,k5x,k5y,k6x,k6y;

  for (int t = 0; t < NT - 1; ++t) {
    const float dt = tsc[t + 1] - tsc[t];

    auto EVAL = [&](float ysx, float ysy, float& kx, float& ky) {
      // ---- L1: 16 h1 rows for my column, straight into B-fragments ----
      h8 bh0, bh1, bl0, bl1;
#pragma unroll
      for (int i = 0; i < 16; ++i) {
        const float hv = tanh_fast(fmaf(w1a[i], ysx, fmaf(w1b[i], ysy, b1r[i])));
        _Float16 a, b; split_f16(hv, a, b);
        if (i < 8) { bh0[i] = a;     bl0[i] = b; }
        else       { bh1[i - 8] = a; bl1[i - 8] = b; }
      }

      // ---- L2: 4 m-tiles x (2 k-steps x 3 split products) MFMA ----
      float p0 = 0.0f, p1 = 0.0f;
#pragma unroll
      for (int mt = 0; mt < 4; ++mt) {
        const h8 ah0 = mkh8(afh[mt][0]), al0 = mkh8(afl[mt][0]);
        const h8 ah1 = mkh8(afh[mt][1]), al1 = mkh8(afl[mt][1]);
        f4 c = { accb[mt][0], accb[mt][1], accb[mt][2], accb[mt][3] };
        c = __builtin_amdgcn_mfma_f32_16x16x32_f16(al0, bh0, c, 0, 0, 0);
        c = __builtin_amdgcn_mfma_f32_16x16x32_f16(ah0, bl0, c, 0, 0, 0);
        c = __builtin_amdgcn_mfma_f32_16x16x32_f16(ah0, bh0, c, 0, 0, 0);
        c = __builtin_amdgcn_mfma_f32_16x16x32_f16(al1, bh1, c, 0, 0, 0);
        c = __builtin_amdgcn_mfma_f32_16x16x32_f16(ah1, bl1, c, 0, 0, 0);
        c = __builtin_amdgcn_mfma_f32_16x16x32_f16(ah1, bh1, c, 0, 0, 0);
        // ---- L3 partials: tanh + W3, rows mt*16+quad*4+r of my column ----
#pragma unroll
        for (int r = 0; r < 4; ++r) {
          const float h2 = tanh_fast(c[r]);
          p0 = fmaf(w30[mt][r], h2, p0);
          p1 = fmaf(w31[mt][r], h2, p1);
        }
      }
      // quad butterfly: lanes col, col^16, col^32, col^48 hold the 4 row-quarters
      p0 += __shfl_xor(p0, 16); p1 += __shfl_xor(p1, 16);
      p0 += __shfl_xor(p0, 32); p1 += __shfl_xor(p1, 32);
      kx = p0 + b30;
      ky = p1 + b31;
    };

    EVAL(yx, yy, k1x, k1y);
    EVAL(fmaf(dt, A21 * k1x, yx), fmaf(dt, A21 * k1y, yy), k2x, k2y);
    {
      float cx = fmaf(A32, k2x, A31 * k1x);
      float cy = fmaf(A32, k2y, A31 * k1y);
      EVAL(fmaf(dt, cx, yx), fmaf(dt, cy, yy), k3x, k3y);
    }
    {
      float cx = fmaf(A43, k3x, fmaf(A42, k2x, A41 * k1x));
      float cy = fmaf(A43, k3y, fmaf(A42, k2y, A41 * k1y));
      EVAL(fmaf(dt, cx, yx), fmaf(dt, cy, yy), k4x, k4y);
    }
    {
      float cx = fmaf(A54, k4x, fmaf(A53, k3x, fmaf(A52, k2x, A51 * k1x)));
      float cy = fmaf(A54, k4y, fmaf(A53, k3y, fmaf(A52, k2y, A51 * k1y)));
      EVAL(fmaf(dt, cx, yx), fmaf(dt, cy, yy), k5x, k5y);
    }
    {
      float cx = fmaf(A65, k5x, fmaf(A64, k4x, fmaf(A63, k3x, fmaf(A62, k2x, A61 * k1x))));
      float cy = fmaf(A65, k5y, fmaf(A64, k4y, fmaf(A63, k3y, fmaf(A62, k2y, A61 * k1y))));
      EVAL(fmaf(dt, cx, yx), fmaf(dt, cy, yy), k6x, k6y);
    }
    {
      float cx = fmaf(BB6, k6x, fmaf(BB5, k5x, fmaf(BB4, k4x, fmaf(BB3, k3x, BB1 * k1x))));
      float cy = fmaf(BB6, k6y, fmaf(BB5, k5y, fmaf(BB4, k4y, fmaf(BB3, k3y, BB1 * k1y))));
      yx = fmaf(dt, cx, yx);
      yy = fmaf(dt, cy, yy);
    }
    if (quad == 0) outv[(t + 1) * NB + gb] = make_float2(yx, yy);
  }
}

extern "C" void kernel_launch(void* const* d_in, const int* in_sizes, int n_in,
                              void* d_out, int out_size, void* d_ws, size_t ws_size,
                              hipStream_t stream) {
  const float* y0 = (const float*)d_in[0];
  const float* ts = (const float*)d_in[1];
  const float* W1 = (const float*)d_in[2];
  const float* b1 = (const float*)d_in[3];
  const float* W2 = (const float*)d_in[4];
  const float* b2 = (const float*)d_in[5];
  const float* W3 = (const float*)d_in[6];
  const float* b3 = (const float*)d_in[7];
  float* out = (float*)d_out;

  node_step_kernel<<<dim3(NB / 64), dim3(256), 0, stream>>>(
      y0, ts, W1, b1, W2, b2, W3, b3, out);
}